// Round 5
// baseline (441.760 us; speedup 1.0000x reference)
//
#include <hip/hip_runtime.h>

// AdaMoeLayer: B=8,S=4096,D=512,E=8 -> T=32768 tokens
// Round 7: R5 geometry (128x128 tile, 256 thr, 2 blocks/CU) + deep pipeline.
//  - A operand: NO LDS. Direct global->reg fragments (lane map row=lane&15,
//    k=(lane>>4)*8), register-double-buffered, loaded 1 step ahead.
//  - B operand: global_load_lds into 3-slot LDS ring (48KB), 2-step lookahead.
//  - End of step: s_waitcnt vmcnt(12) (12 = this step's issues: 4 B-lds + 8
//    A-reg) + raw s_barrier. The s+1 B batch is always older -> drained.
//  - Expert fold every 8 steps (acc += w*tmp); bias in epilogue (R6-verified).
//  - Even/odd steps hand-unrolled so a0/a1 register indexing is static.

#define T_TOKENS 32768
#define DDIM 512
#define KDIM 4096
#define SLOTB 8192   // ushorts per B slot (128 rows x 64 k)

typedef __attribute__((ext_vector_type(8))) short short8;
typedef __attribute__((ext_vector_type(4))) float floatx4;
typedef __bf16 bf16x2 __attribute__((ext_vector_type(2)));

__device__ __forceinline__ unsigned short f2bf(float f) {
    unsigned int u = __float_as_uint(f);
    u += 0x7FFFu + ((u >> 16) & 1u);   // RNE
    return (unsigned short)(u >> 16);
}

__device__ __forceinline__ unsigned int pk2(float a, float b) {
#if __has_builtin(__builtin_amdgcn_cvt_pk_bf16_f32)
    bf16x2 v = __builtin_amdgcn_cvt_pk_bf16_f32(a, b);
    return __builtin_bit_cast(unsigned int, v);
#else
    return (unsigned int)f2bf(a) | ((unsigned int)f2bf(b) << 16);
#endif
}

__device__ __forceinline__ void async_copy16(const void* g, void* l) {
    __builtin_amdgcn_global_load_lds(
        (const __attribute__((address_space(1))) void*)g,
        (__attribute__((address_space(3))) void*)l, 16, 0, 0);
}

// ------- Kernel 1: gating (fp32) -> wbuf[T,8]  +  x -> bf16 Xbf[T,512] ------
__global__ __launch_bounds__(256) void gating_cvt(
    const float* __restrict__ x, const float* __restrict__ Wg,
    const float* __restrict__ bg, const float* __restrict__ Wt,
    const float* __restrict__ bt, float* __restrict__ wbuf,
    unsigned short* __restrict__ Xbf)
{
    __shared__ float sW[512 * 12];  // [d][12]: e<8 gate cols, e==8 thr col
    const int tid = threadIdx.x;
    for (int i = tid; i < 512 * 9; i += 256) {
        int d = i / 9, e = i - d * 9;
        sW[d * 12 + e] = (e < 8) ? Wg[d * 8 + e] : Wt[d];
    }
    __syncthreads();

    const int t = blockIdx.x * 64 + (tid >> 2);
    const int q = tid & 3;
    float g[9];
#pragma unroll
    for (int e = 0; e < 9; ++e) g[e] = 0.f;

    const float4* xr = (const float4*)(x + (size_t)t * 512 + q * 128);
    for (int i = 0; i < 32; ++i) {
        float4 v = xr[i];
        float xv[4] = {v.x, v.y, v.z, v.w};
        const float* wp = &sW[(q * 128 + i * 4) * 12];
#pragma unroll
        for (int c = 0; c < 4; ++c) {
            const float* w = wp + c * 12;
#pragma unroll
            for (int e = 0; e < 9; ++e) g[e] = fmaf(xv[c], w[e], g[e]);
        }
    }
#pragma unroll
    for (int e = 0; e < 9; ++e) {
        g[e] += __shfl_xor(g[e], 1);
        g[e] += __shfl_xor(g[e], 2);
    }
    if (q == 0) {
#pragma unroll
        for (int e = 0; e < 8; ++e) g[e] += bg[e];
        g[8] += bt[0];
        float m = g[0];
#pragma unroll
        for (int e = 1; e < 8; ++e) m = fmaxf(m, g[e]);
        float s = 0.f;
        float p[8];
#pragma unroll
        for (int e = 0; e < 8; ++e) { p[e] = __expf(g[e] - m); s += p[e]; }
        const float inv = 1.f / s;
        const float thr = 0.25f / (1.f + __expf(-g[8]));
        float w8[8];
        float ws = 0.f;
#pragma unroll
        for (int e = 0; e < 8; ++e) {
            float a = p[e] * inv - thr;
            w8[e] = a > 0.f ? a : 0.f;
            ws += w8[e];
        }
        if (ws == 0.f) ws = 1.f;
        const float invw = 1.f / ws;
        float4 o0, o1;
        o0.x = w8[0] * invw; o0.y = w8[1] * invw; o0.z = w8[2] * invw; o0.w = w8[3] * invw;
        o1.x = w8[4] * invw; o1.y = w8[5] * invw; o1.z = w8[6] * invw; o1.w = w8[7] * invw;
        float4* op = (float4*)(wbuf + (size_t)t * 8);
        op[0] = o0;
        op[1] = o1;
    }

    // conversion pass: this block's 64 tokens = 32768 floats, coalesced (L2-hot)
    const size_t base = (size_t)blockIdx.x * 64 * 512;
    const float4* xs = (const float4*)(x + base);
    uint2* xd = (uint2*)(Xbf + base);
#pragma unroll 4
    for (int it = 0; it < 32; ++it) {
        float4 v = xs[it * 256 + tid];
        uint2 pk;
        pk.x = pk2(v.x, v.y);
        pk.y = pk2(v.z, v.w);
        xd[it * 256 + tid] = pk;
    }
}

// ------------- Kernel 2: build Bt[512][4096] bf16 (transpose W_exp) --------
__global__ __launch_bounds__(256) void build_bt(
    const float* __restrict__ Wexp, unsigned short* __restrict__ Bt)
{
    __shared__ float tile[64][65];
    const int k0 = blockIdx.x * 64;
    const int n0 = blockIdx.y * 64;
    const int tid = threadIdx.x;
    const int r = tid >> 4, cq = tid & 15;
#pragma unroll
    for (int p = 0; p < 4; ++p) {
        const int rr = p * 16 + r;
        const float4 v = *(const float4*)(Wexp + (size_t)(k0 + rr) * 512 + n0 + cq * 4);
        tile[rr][cq * 4 + 0] = v.x;
        tile[rr][cq * 4 + 1] = v.y;
        tile[rr][cq * 4 + 2] = v.z;
        tile[rr][cq * 4 + 3] = v.w;
    }
    __syncthreads();
    const int rn = tid >> 2;  // output row (n), 0..63
    const int kq = tid & 3;   // 16-wide k chunk
    alignas(16) unsigned short buf[16];
#pragma unroll
    for (int j = 0; j < 16; ++j) buf[j] = f2bf(tile[kq * 16 + j][rn]);
    unsigned short* dst = Bt + (size_t)(n0 + rn) * KDIM + k0 + kq * 16;
    *(uint4*)(dst) = *(const uint4*)(buf);
    *(uint4*)(dst + 8) = *(const uint4*)(buf + 8);
}

// ------------- Kernel 3: main GEMM, 128x128, A-in-reg + B 3-slot ring ------
// B LDS element (row,k) at row*64 + ((k/8 ^ (row&7))*8)+k%8 (ushort index),
// staged by global_load_lds with lane->global chunk perm cg=(lane&7)^(lane>>3).
// Step s = e*8+ks (BK=64). B(s+2) staged at step s; A(s+1) reg-loaded at s.
__global__ __launch_bounds__(256, 2) void moe_gemm(
    const unsigned short* __restrict__ Xbf, const float* __restrict__ wbuf,
    const float* __restrict__ bexp, const unsigned short* __restrict__ Bt,
    float* __restrict__ out)
{
    __shared__ alignas(16) unsigned short Bs[3 * SLOTB];  // 48 KB
    __shared__ float sWbT[8 * 128];                       // 4 KB, [e][row]

    const int tid = threadIdx.x;
    const int wave = tid >> 6;      // 0..3
    const int lane = tid & 63;
    const int wm = wave >> 1;       // 0..1: 64-row half
    const int wn = wave & 1;        // 0..1: 64-col half
    const int lm = lane & 15;
    const int lq = lane >> 4;
    const int brow = lane >> 3;
    const int cg = (lane & 7) ^ brow;  // lane->global chunk permutation (B)

    // XCD co-location (R5-proven): hw XCD = lin%8; 4 n-blocks of a t-tile are
    // consecutive j (share the Xbf t-slice in that XCD's L2).
    const int lin = blockIdx.x;
    const int g = lin & 7;
    const int j_ = lin >> 3;
    const int t0 = (g * 32 + (j_ >> 2)) * 128;
    const int n0 = (j_ & 3) * 128;

    // sWbT[e][row] = wbuf[t0+row][e]  (transposed so fold reads are b128)
    {
        const int row = tid >> 1, half = tid & 1;
        const float4 wv4 = *(const float4*)(wbuf + (size_t)(t0 + row) * 8 + half * 4);
        sWbT[(half * 4 + 0) * 128 + row] = wv4.x;
        sWbT[(half * 4 + 1) * 128 + row] = wv4.y;
        sWbT[(half * 4 + 2) * 128 + row] = wv4.z;
        sWbT[(half * 4 + 3) * 128 + row] = wv4.w;
    }

    // A fragment base: row = t0 + wm*64 + i*16 + lm, k-chunk lq*8 (+kk*32 +d0)
    const unsigned short* xbase = Xbf + (size_t)(t0 + wm * 64 + lm) * 512 + lq * 8;

#define STAGE_B(s_, slot_)                                                      \
    {                                                                           \
        const int k0_ = (s_) << 6;                                              \
        _Pragma("unroll")                                                       \
        for (int i = 0; i < 4; ++i)                                             \
            async_copy16(Bt + (size_t)(n0 + wave * 32 + i * 8 + brow) * KDIM + k0_ + cg * 8, \
                         Bs + (slot_) * SLOTB + (wave * 32 + i * 8) * 64);      \
    }

#define LOAD_A(s_, dst)                                                         \
    {                                                                           \
        const int d0_ = ((s_) & 7) << 6;                                        \
        _Pragma("unroll")                                                       \
        for (int i = 0; i < 4; ++i)                                             \
            _Pragma("unroll")                                                   \
            for (int kk = 0; kk < 2; ++kk)                                      \
                dst[i][kk] = *(const short8*)(xbase + i * 16 * 512 + d0_ + kk * 32); \
    }

#define COMPUTE(slot_, areg)                                                    \
    {                                                                           \
        const unsigned short* Bb = Bs + (slot_) * SLOTB;                        \
        __builtin_amdgcn_s_setprio(1);                                          \
        _Pragma("unroll")                                                       \
        for (int kk = 0; kk < 2; ++kk) {                                        \
            const int ch = kk * 4 + lq;                                         \
            short8 b[4];                                                        \
            _Pragma("unroll")                                                   \
            for (int j = 0; j < 4; ++j) {                                       \
                const int row = wn * 64 + j * 16 + lm;                          \
                b[j] = *(const short8*)(Bb + row * 64 + ((ch ^ (row & 7)) << 3)); \
            }                                                                   \
            _Pragma("unroll")                                                   \
            for (int i = 0; i < 4; ++i)                                         \
                _Pragma("unroll")                                               \
                for (int j = 0; j < 4; ++j)                                     \
                    tmp[i][j] = __builtin_amdgcn_mfma_f32_16x16x32_bf16(        \
                        areg[i][kk], b[j], tmp[i][j], 0, 0, 0);                 \
        }                                                                       \
        __builtin_amdgcn_s_setprio(0);                                          \
    }

#define FOLD(e_)                                                                \
    {                                                                           \
        _Pragma("unroll")                                                       \
        for (int i = 0; i < 4; ++i) {                                           \
            const float4 wq = *(const float4*)(sWbT + (e_) * 128 + wm * 64 + i * 16 + lq * 4); \
            _Pragma("unroll")                                                   \
            for (int j = 0; j < 4; ++j) {                                       \
                acc[i][j][0] = fmaf(wq.x, tmp[i][j][0], acc[i][j][0]);          \
                acc[i][j][1] = fmaf(wq.y, tmp[i][j][1], acc[i][j][1]);          \
                acc[i][j][2] = fmaf(wq.z, tmp[i][j][2], acc[i][j][2]);          \
                acc[i][j][3] = fmaf(wq.w, tmp[i][j][3], acc[i][j][3]);          \
                tmp[i][j] = (floatx4){0.f, 0.f, 0.f, 0.f};                      \
            }                                                                   \
        }                                                                       \
    }

#define SYNC12()                                                                \
    {                                                                           \
        __builtin_amdgcn_sched_barrier(0);                                      \
        asm volatile("s_waitcnt vmcnt(12)" ::: "memory");                       \
        __builtin_amdgcn_s_barrier();                                           \
        __builtin_amdgcn_sched_barrier(0);                                      \
    }

    floatx4 acc[4][4], tmp[4][4];
#pragma unroll
    for (int i = 0; i < 4; ++i)
#pragma unroll
        for (int j = 0; j < 4; ++j) {
            acc[i][j] = (floatx4){0.f, 0.f, 0.f, 0.f};
            tmp[i][j] = (floatx4){0.f, 0.f, 0.f, 0.f};
        }

    short8 a0[4][2], a1[4][2];

    // prologue: B slots 0,1 staged; A(0) in regs; full drain (covers sWbT too)
    STAGE_B(0, 0);
    STAGE_B(1, 1);
    LOAD_A(0, a0);
    __syncthreads();

    int sl = 0;  // slot of even step s0 = 2m
    for (int m = 0; m < 32; ++m) {
        const int s0 = 2 * m;
        const int sl1 = (sl >= 2) ? sl - 2 : sl + 1;  // (sl+1)%3
        const int sl2 = (sl >= 1) ? sl - 1 : sl + 2;  // (sl+2)%3

        // ---- even step s0: compute a0, prefetch B(s0+2), A(s0+1)->a1 ----
        if (m < 31) STAGE_B(s0 + 2, sl2);
        LOAD_A(s0 + 1, a1);
        COMPUTE(sl, a0);
        // s0 even -> never an expert boundary
        if (m < 31) {
            SYNC12();   // issued this step: 4 B-lds + 8 A-reg = 12
        } else {
            __builtin_amdgcn_sched_barrier(0);
            asm volatile("s_waitcnt vmcnt(8)" ::: "memory");  // only A(63) out
            __builtin_amdgcn_s_barrier();
            __builtin_amdgcn_sched_barrier(0);
        }

        // ---- odd step s1 = s0+1: compute a1, prefetch B(s1+2), A(s1+1)->a0 --
        const int s1 = s0 + 1;
        if (m < 31) {
            STAGE_B(s1 + 2, sl);  // (sl1+2)%3 == sl
            LOAD_A(s1 + 1, a0);
        }
        COMPUTE(sl1, a1);
        if ((m & 3) == 3) FOLD(s1 >> 3);   // s1 = 7,15,...,63
        if (m < 31) SYNC12();
        // else: last step, fall through to epilogue

        sl = sl2;  // advance by 2 steps
    }

    // epilogue: out = acc + sum_e w[t,e]*b_exp[e,col]
    float bc[4][8];
#pragma unroll
    for (int j = 0; j < 4; ++j) {
        const int col = n0 + wn * 64 + j * 16 + lm;
#pragma unroll
        for (int e = 0; e < 8; ++e) bc[j][e] = bexp[e * 512 + col];
    }
#pragma unroll
    for (int i = 0; i < 4; ++i)
#pragma unroll
        for (int r = 0; r < 4; ++r) {
            const int rowl = wm * 64 + i * 16 + lq * 4 + r;
            const float4 w0 = *(const float4*)(wbuf + (size_t)(t0 + rowl) * 8);
            const float4 w1 = *(const float4*)(wbuf + (size_t)(t0 + rowl) * 8 + 4);
            float* op = out + (size_t)(t0 + rowl) * 512 + n0 + wn * 64 + lm;
#pragma unroll
            for (int j = 0; j < 4; ++j) {
                float bias = w0.x * bc[j][0];
                bias = fmaf(w0.y, bc[j][1], bias);
                bias = fmaf(w0.z, bc[j][2], bias);
                bias = fmaf(w0.w, bc[j][3], bias);
                bias = fmaf(w1.x, bc[j][4], bias);
                bias = fmaf(w1.y, bc[j][5], bias);
                bias = fmaf(w1.z, bc[j][6], bias);
                bias = fmaf(w1.w, bc[j][7], bias);
                op[j * 16] = acc[i][j][r] + bias;
            }
        }
#undef STAGE_B
#undef LOAD_A
#undef COMPUTE
#undef FOLD
#undef SYNC12
}

extern "C" void kernel_launch(void* const* d_in, const int* in_sizes, int n_in,
                              void* d_out, int out_size, void* d_ws, size_t ws_size,
                              hipStream_t stream) {
    const float* x   = (const float*)d_in[0];
    const float* Wg  = (const float*)d_in[1];
    const float* bg  = (const float*)d_in[2];
    const float* Wt  = (const float*)d_in[3];
    const float* bt  = (const float*)d_in[4];
    const float* Wex = (const float*)d_in[5];
    const float* bex = (const float*)d_in[6];
    float* out = (float*)d_out;

    // ws layout: Xbf bf16 [32768][512] = 32 MB; Bt bf16 [512][4096] = 4 MB;
    //            wbuf fp32 [32768][8] = 1 MB.  Total 37 MB.
    unsigned short* Xbf = (unsigned short*)d_ws;
    unsigned short* Bt  = (unsigned short*)((char*)d_ws + (size_t)T_TOKENS * DDIM * 2);
    float* wbuf = (float*)((char*)d_ws + (size_t)T_TOKENS * DDIM * 2
                                       + (size_t)DDIM * KDIM * 2);

    gating_cvt<<<T_TOKENS / 64, 256, 0, stream>>>(x, Wg, bg, Wt, bt, wbuf, Xbf);
    build_bt<<<dim3(KDIM / 64, DDIM / 64), 256, 0, stream>>>(Wex, Bt);
    moe_gemm<<<1024, 256, 0, stream>>>(Xbf, wbuf, bex, Bt, out);
}

// Round 7
// 290.099 us; speedup vs baseline: 1.5228x; 1.5228x over previous
//
#include <hip/hip_runtime.h>

// AdaMoeLayer: B=8,S=4096,D=512,E=8 -> T=32768 tokens
// Round 9: R8 pipeline with the work-decomposition bug fixed (grid 256->512;
// t0 covers all 256 t-tiles). R8's absmax 5.3 was half-unwritten output, not
// a race. Structure: fine-grained 2-phase interleave (m201-style T3+T4+T5).
//  - 512 thr (8 waves 2Mx4N), 128x256 tile, BK=64, 3-slot LDS ring (A and B),
//    2-step lookahead, 148KB LDS, grid=512.
//  - Per K-step: 2 phases (kk=0/1). Each phase: {ds_read 8x b128 || issue
//    stage loads for s+2} -> s_barrier -> setprio(1) 16 MFMA setprio(0) ->
//    s_barrier. Counted s_waitcnt vmcnt(6) ONCE per step (drains only the
//    s+1 batch); vmcnt(0) only at s=62. NO sched_barrier (R7/m141 lesson).
//  - Expert fold (acc += w*tmp) every 8 steps; bias in epilogue.

#define T_TOKENS 32768
#define DDIM 512
#define KDIM 4096
#define SLOTA 8192   // ushorts per A slot (128 rows x 64 k)
#define SLOTB 16384  // ushorts per B slot (256 rows x 64 k)

typedef __attribute__((ext_vector_type(8))) short short8;
typedef __attribute__((ext_vector_type(4))) float floatx4;
typedef __bf16 bf16x2 __attribute__((ext_vector_type(2)));

__device__ __forceinline__ unsigned short f2bf(float f) {
    unsigned int u = __float_as_uint(f);
    u += 0x7FFFu + ((u >> 16) & 1u);   // RNE
    return (unsigned short)(u >> 16);
}

__device__ __forceinline__ unsigned int pk2(float a, float b) {
#if __has_builtin(__builtin_amdgcn_cvt_pk_bf16_f32)
    bf16x2 v = __builtin_amdgcn_cvt_pk_bf16_f32(a, b);
    return __builtin_bit_cast(unsigned int, v);
#else
    return (unsigned int)f2bf(a) | ((unsigned int)f2bf(b) << 16);
#endif
}

__device__ __forceinline__ void async_copy16(const void* g, void* l) {
    __builtin_amdgcn_global_load_lds(
        (const __attribute__((address_space(1))) void*)g,
        (__attribute__((address_space(3))) void*)l, 16, 0, 0);
}

// ------- Kernel 1: gating (fp32) -> wbuf[T,8]  +  x -> bf16 Xbf[T,512] ------
__global__ __launch_bounds__(256) void gating_cvt(
    const float* __restrict__ x, const float* __restrict__ Wg,
    const float* __restrict__ bg, const float* __restrict__ Wt,
    const float* __restrict__ bt, float* __restrict__ wbuf,
    unsigned short* __restrict__ Xbf)
{
    __shared__ float sW[512 * 12];  // [d][12]: e<8 gate cols, e==8 thr col
    const int tid = threadIdx.x;
    for (int i = tid; i < 512 * 9; i += 256) {
        int d = i / 9, e = i - d * 9;
        sW[d * 12 + e] = (e < 8) ? Wg[d * 8 + e] : Wt[d];
    }
    __syncthreads();

    const int t = blockIdx.x * 64 + (tid >> 2);
    const int q = tid & 3;
    float g[9];
#pragma unroll
    for (int e = 0; e < 9; ++e) g[e] = 0.f;

    const float4* xr = (const float4*)(x + (size_t)t * 512 + q * 128);
    for (int i = 0; i < 32; ++i) {
        float4 v = xr[i];
        float xv[4] = {v.x, v.y, v.z, v.w};
        const float* wp = &sW[(q * 128 + i * 4) * 12];
#pragma unroll
        for (int c = 0; c < 4; ++c) {
            const float* w = wp + c * 12;
#pragma unroll
            for (int e = 0; e < 9; ++e) g[e] = fmaf(xv[c], w[e], g[e]);
        }
    }
#pragma unroll
    for (int e = 0; e < 9; ++e) {
        g[e] += __shfl_xor(g[e], 1);
        g[e] += __shfl_xor(g[e], 2);
    }
    if (q == 0) {
#pragma unroll
        for (int e = 0; e < 8; ++e) g[e] += bg[e];
        g[8] += bt[0];
        float m = g[0];
#pragma unroll
        for (int e = 1; e < 8; ++e) m = fmaxf(m, g[e]);
        float s = 0.f;
        float p[8];
#pragma unroll
        for (int e = 0; e < 8; ++e) { p[e] = __expf(g[e] - m); s += p[e]; }
        const float inv = 1.f / s;
        const float thr = 0.25f / (1.f + __expf(-g[8]));
        float w8[8];
        float ws = 0.f;
#pragma unroll
        for (int e = 0; e < 8; ++e) {
            float a = p[e] * inv - thr;
            w8[e] = a > 0.f ? a : 0.f;
            ws += w8[e];
        }
        if (ws == 0.f) ws = 1.f;
        const float invw = 1.f / ws;
        float4 o0, o1;
        o0.x = w8[0] * invw; o0.y = w8[1] * invw; o0.z = w8[2] * invw; o0.w = w8[3] * invw;
        o1.x = w8[4] * invw; o1.y = w8[5] * invw; o1.z = w8[6] * invw; o1.w = w8[7] * invw;
        float4* op = (float4*)(wbuf + (size_t)t * 8);
        op[0] = o0;
        op[1] = o1;
    }

    // conversion pass: this block's 64 tokens = 32768 floats, coalesced (L2-hot)
    const size_t base = (size_t)blockIdx.x * 64 * 512;
    const float4* xs = (const float4*)(x + base);
    uint2* xd = (uint2*)(Xbf + base);
#pragma unroll 4
    for (int it = 0; it < 32; ++it) {
        float4 v = xs[it * 256 + tid];
        uint2 pk;
        pk.x = pk2(v.x, v.y);
        pk.y = pk2(v.z, v.w);
        xd[it * 256 + tid] = pk;
    }
}

// ------------- Kernel 2: build Bt[512][4096] bf16 (transpose W_exp) --------
__global__ __launch_bounds__(256) void build_bt(
    const float* __restrict__ Wexp, unsigned short* __restrict__ Bt)
{
    __shared__ float tile[64][65];
    const int k0 = blockIdx.x * 64;
    const int n0 = blockIdx.y * 64;
    const int tid = threadIdx.x;
    const int r = tid >> 4, cq = tid & 15;
#pragma unroll
    for (int p = 0; p < 4; ++p) {
        const int rr = p * 16 + r;
        const float4 v = *(const float4*)(Wexp + (size_t)(k0 + rr) * 512 + n0 + cq * 4);
        tile[rr][cq * 4 + 0] = v.x;
        tile[rr][cq * 4 + 1] = v.y;
        tile[rr][cq * 4 + 2] = v.z;
        tile[rr][cq * 4 + 3] = v.w;
    }
    __syncthreads();
    const int rn = tid >> 2;  // output row (n), 0..63
    const int kq = tid & 3;   // 16-wide k chunk
    alignas(16) unsigned short buf[16];
#pragma unroll
    for (int j = 0; j < 16; ++j) buf[j] = f2bf(tile[kq * 16 + j][rn]);
    unsigned short* dst = Bt + (size_t)(n0 + rn) * KDIM + k0 + kq * 16;
    *(uint4*)(dst) = *(const uint4*)(buf);
    *(uint4*)(dst + 8) = *(const uint4*)(buf + 8);
}

// ------------- Kernel 3: main GEMM, 128x256, 3-slot ring, 2-phase/step -----
// LDS element (row,k) at row*64 + ((k/8 ^ (row&7))*8)+k%8 (ushort index).
// Staged by global_load_lds with lane->global chunk perm cg=(lane&7)^(lane>>3).
__global__ __launch_bounds__(512, 2) void moe_gemm(
    const unsigned short* __restrict__ Xbf, const float* __restrict__ wbuf,
    const float* __restrict__ bexp, const unsigned short* __restrict__ Bt,
    float* __restrict__ out)
{
    __shared__ alignas(16) unsigned short As[3 * SLOTA];  // 48 KB
    __shared__ alignas(16) unsigned short Bs[3 * SLOTB];  // 96 KB
    __shared__ float sWbT[8 * 128];                       // 4 KB, [e][row]

    const int tid = threadIdx.x;
    const int wave = tid >> 6;      // 0..7
    const int lane = tid & 63;
    const int wm = wave >> 2;       // 0..1: 64-row half
    const int wn = wave & 3;        // 0..3: 64-col quarter
    const int lm = lane & 15;
    const int lq = lane >> 4;
    const int brow = lane >> 3;
    const int cg = (lane & 7) ^ brow;  // lane->global chunk permutation

    // XCD co-location: hw XCD = lin%8; the 2 n-blocks of a t-tile are
    // consecutive j (share the Xbf t-slice in that XCD's L2).
    // grid=512: 256 t-tiles x 2 n-tiles (R6-verified decomposition).
    const int lin = blockIdx.x;
    const int g = lin & 7;
    const int j_ = lin >> 3;                 // 0..63
    const int t0 = (g * 32 + (j_ >> 1)) * 128;
    const int n0 = (j_ & 1) * 256;

    // sWbT[e][row] = wbuf[t0+row][e]  (transposed so fold reads are b128)
    {
        const int row = tid & 127, q = tid >> 7;  // q = 0..3
        const float2 w2 = *(const float2*)(wbuf + (size_t)(t0 + row) * 8 + q * 2);
        sWbT[(q * 2 + 0) * 128 + row] = w2.x;
        sWbT[(q * 2 + 1) * 128 + row] = w2.y;
    }

    // staging: per thread 2 A loads (128 rows) + 4 B loads (256 rows)
#define STAGE_A(s_, slot_)                                                      \
    {                                                                           \
        const int d0_ = ((s_) & 7) << 6;                                        \
        _Pragma("unroll")                                                       \
        for (int i = 0; i < 2; ++i)                                             \
            async_copy16(Xbf + (size_t)(t0 + wave * 16 + i * 8 + brow) * 512 + d0_ + cg * 8, \
                         As + (slot_) * SLOTA + (wave * 16 + i * 8) * 64);      \
    }
#define STAGE_B(s_, slot_, i0, i1)                                              \
    {                                                                           \
        const int k0_ = (s_) << 6;                                              \
        _Pragma("unroll")                                                       \
        for (int i = (i0); i < (i1); ++i)                                       \
            async_copy16(Bt + (size_t)(n0 + wave * 32 + i * 8 + brow) * KDIM + k0_ + cg * 8, \
                         Bs + (slot_) * SLOTB + (wave * 32 + i * 8) * 64);      \
    }

    // prologue: slots 0 and 1 staged; full drain (also covers sWbT ds_writes)
    STAGE_A(0, 0);
    STAGE_B(0, 0, 0, 4);
    STAGE_A(1, 1);
    STAGE_B(1, 1, 0, 4);
    __syncthreads();

    floatx4 acc[4][4], tmp[4][4];
#pragma unroll
    for (int i = 0; i < 4; ++i)
#pragma unroll
        for (int j = 0; j < 4; ++j) {
            acc[i][j] = (floatx4){0.f, 0.f, 0.f, 0.f};
            tmp[i][j] = (floatx4){0.f, 0.f, 0.f, 0.f};
        }

    int sl = 0;  // slot holding step s
    for (int s = 0; s < 64; ++s) {
        const int sl1 = (sl == 2) ? 0 : sl + 1;  // (sl+1)%3
        const int sl2 = (sl == 0) ? 2 : sl - 1;  // (sl+2)%3
        const unsigned short* Ab = As + sl * SLOTA;
        const unsigned short* Bb = Bs + sl * SLOTB;

        // ================= phase 0 (kk=0): ds_read || stage-issue ==========
        {
            short8 a[4], b[4];
            const int ch = lq;
#pragma unroll
            for (int i = 0; i < 4; ++i) {
                const int row = wm * 64 + i * 16 + lm;
                a[i] = *(const short8*)(Ab + row * 64 + ((ch ^ (row & 7)) << 3));
            }
#pragma unroll
            for (int j = 0; j < 4; ++j) {
                const int row = wn * 64 + j * 16 + lm;
                b[j] = *(const short8*)(Bb + row * 64 + ((ch ^ (row & 7)) << 3));
            }
            if (s < 62) {
                STAGE_A(s + 2, sl2);
                STAGE_B(s + 2, sl2, 0, 2);
            }
            __builtin_amdgcn_s_barrier();
            __builtin_amdgcn_s_setprio(1);
#pragma unroll
            for (int i = 0; i < 4; ++i)
#pragma unroll
                for (int j = 0; j < 4; ++j)
                    tmp[i][j] = __builtin_amdgcn_mfma_f32_16x16x32_bf16(
                        a[i], b[j], tmp[i][j], 0, 0, 0);
            __builtin_amdgcn_s_setprio(0);
            __builtin_amdgcn_s_barrier();
        }

        // ================= phase 1 (kk=1): ds_read || stage-issue ==========
        {
            short8 a[4], b[4];
            const int ch = 4 + lq;
#pragma unroll
            for (int i = 0; i < 4; ++i) {
                const int row = wm * 64 + i * 16 + lm;
                a[i] = *(const short8*)(Ab + row * 64 + ((ch ^ (row & 7)) << 3));
            }
#pragma unroll
            for (int j = 0; j < 4; ++j) {
                const int row = wn * 64 + j * 16 + lm;
                b[j] = *(const short8*)(Bb + row * 64 + ((ch ^ (row & 7)) << 3));
            }
            if (s < 62) {
                STAGE_B(s + 2, sl2, 2, 4);
            }
            __builtin_amdgcn_s_barrier();
            __builtin_amdgcn_s_setprio(1);
#pragma unroll
            for (int i = 0; i < 4; ++i)
#pragma unroll
                for (int j = 0; j < 4; ++j)
                    tmp[i][j] = __builtin_amdgcn_mfma_f32_16x16x32_bf16(
                        a[i], b[j], tmp[i][j], 0, 0, 0);
            __builtin_amdgcn_s_setprio(0);
        }

        // ---- expert boundary: fold acc += w[t,e]*tmp, reinit tmp ----
        if ((s & 7) == 7) {
            const int e = s >> 3;
#pragma unroll
            for (int i = 0; i < 4; ++i) {
                const float4 wq = *(const float4*)(sWbT + e * 128 + wm * 64 + i * 16 + lq * 4);
#pragma unroll
                for (int j = 0; j < 4; ++j) {
                    acc[i][j][0] = fmaf(wq.x, tmp[i][j][0], acc[i][j][0]);
                    acc[i][j][1] = fmaf(wq.y, tmp[i][j][1], acc[i][j][1]);
                    acc[i][j][2] = fmaf(wq.z, tmp[i][j][2], acc[i][j][2]);
                    acc[i][j][3] = fmaf(wq.w, tmp[i][j][3], acc[i][j][3]);
                    tmp[i][j] = (floatx4){0.f, 0.f, 0.f, 0.f};
                }
            }
        }

        // ---- counted drain: only the s+1 batch (older) must have landed ----
        if (s < 62) {
            asm volatile("s_waitcnt vmcnt(6)" ::: "memory");
        } else if (s == 62) {
            asm volatile("s_waitcnt vmcnt(0)" ::: "memory");
        }
        __builtin_amdgcn_s_barrier();
        sl = sl1;
    }

    // epilogue: out = acc + sum_e w[t,e]*b_exp[e,col]
    float bc[4][8];
#pragma unroll
    for (int j = 0; j < 4; ++j) {
        const int col = n0 + wn * 64 + j * 16 + lm;
#pragma unroll
        for (int e = 0; e < 8; ++e) bc[j][e] = bexp[e * 512 + col];
    }
#pragma unroll
    for (int i = 0; i < 4; ++i)
#pragma unroll
        for (int r = 0; r < 4; ++r) {
            const int rowl = wm * 64 + i * 16 + lq * 4 + r;
            const float4 w0 = *(const float4*)(wbuf + (size_t)(t0 + rowl) * 8);
            const float4 w1 = *(const float4*)(wbuf + (size_t)(t0 + rowl) * 8 + 4);
            float* op = out + (size_t)(t0 + rowl) * 512 + n0 + wn * 64 + lm;
#pragma unroll
            for (int j = 0; j < 4; ++j) {
                float bias = w0.x * bc[j][0];
                bias = fmaf(w0.y, bc[j][1], bias);
                bias = fmaf(w0.z, bc[j][2], bias);
                bias = fmaf(w0.w, bc[j][3], bias);
                bias = fmaf(w1.x, bc[j][4], bias);
                bias = fmaf(w1.y, bc[j][5], bias);
                bias = fmaf(w1.z, bc[j][6], bias);
                bias = fmaf(w1.w, bc[j][7], bias);
                op[j * 16] = acc[i][j][r] + bias;
            }
        }
#undef STAGE_A
#undef STAGE_B
}

extern "C" void kernel_launch(void* const* d_in, const int* in_sizes, int n_in,
                              void* d_out, int out_size, void* d_ws, size_t ws_size,
                              hipStream_t stream) {
    const float* x   = (const float*)d_in[0];
    const float* Wg  = (const float*)d_in[1];
    const float* bg  = (const float*)d_in[2];
    const float* Wt  = (const float*)d_in[3];
    const float* bt  = (const float*)d_in[4];
    const float* Wex = (const float*)d_in[5];
    const float* bex = (const float*)d_in[6];
    float* out = (float*)d_out;

    // ws layout: Xbf bf16 [32768][512] = 32 MB; Bt bf16 [512][4096] = 4 MB;
    //            wbuf fp32 [32768][8] = 1 MB.  Total 37 MB.
    unsigned short* Xbf = (unsigned short*)d_ws;
    unsigned short* Bt  = (unsigned short*)((char*)d_ws + (size_t)T_TOKENS * DDIM * 2);
    float* wbuf = (float*)((char*)d_ws + (size_t)T_TOKENS * DDIM * 2
                                       + (size_t)DDIM * KDIM * 2);

    gating_cvt<<<T_TOKENS / 64, 256, 0, stream>>>(x, Wg, bg, Wt, bt, wbuf, Xbf);
    build_bt<<<dim3(KDIM / 64, DDIM / 64), 256, 0, stream>>>(Wex, Bt);
    moe_gemm<<<512, 512, 0, stream>>>(Xbf, wbuf, bex, Bt, out);
}

// Round 8
// 286.707 us; speedup vs baseline: 1.5408x; 1.0118x over previous
//
#include <hip/hip_runtime.h>

// AdaMoeLayer: B=8,S=4096,D=512,E=8 -> T=32768 tokens
// Round 10: single-GEMM (w folded into A at stage time, once per element) on
// the m201 256x256 geometry. out = Ahat @ Bt + bias-epilogue, where
// Ahat[t, e*512+d] = w[t,e]*bf16(x[t,d]) (scaled in f32, rounded once more).
// No expert fold -> no tmp -> wave-tile 128x64 (acc[8][4], 64 MFMA/step/wave).
//  - 512 thr, 8 waves (2M x 4N). BM=256 BN=256 BK=64, K=4096, 64 steps.
//  - B: global_load_lds 3-slot ring (96KB), 2-step lookahead, pre-swizzled src.
//  - A: reg-staged (Xbf->reg at P0 for s+1; scale+swizzled ds_write at P3),
//    SINGLE 32KB slot (all reads of A(s) complete before P3 writes A(s+1)).
//  - 4 phases/step: {ds_read subtile || issue loads} barrier setprio 16xMFMA
//    setprio barrier. vmcnt(4) once per step at P3 (drains B(s+1)+A(s+1) regs,
//    keeps B(s+2) in flight). lgkmcnt(0) before end-of-step barrier (raw
//    s_barrier does NOT drain ds_writes). NO sched_barrier.
//  - grid 256 (128 t-tiles x 2 n-halves), 1 block/CU, XCD-paired.

#define T_TOKENS 32768
#define DDIM 512
#define KDIM 4096
#define SLOTB 16384  // ushorts per B slot (256 rows x 64 k)
#define SLOTA 16384  // ushorts A slot (256 rows x 64 k)

typedef __attribute__((ext_vector_type(8))) short short8;
typedef __attribute__((ext_vector_type(4))) float floatx4;
typedef __bf16 bf16x2 __attribute__((ext_vector_type(2)));

__device__ __forceinline__ unsigned short f2bf(float f) {
    unsigned int u = __float_as_uint(f);
    u += 0x7FFFu + ((u >> 16) & 1u);   // RNE
    return (unsigned short)(u >> 16);
}

__device__ __forceinline__ unsigned int pk2(float a, float b) {
#if __has_builtin(__builtin_amdgcn_cvt_pk_bf16_f32)
    bf16x2 v = __builtin_amdgcn_cvt_pk_bf16_f32(a, b);
    return __builtin_bit_cast(unsigned int, v);
#else
    return (unsigned int)f2bf(a) | ((unsigned int)f2bf(b) << 16);
#endif
}

__device__ __forceinline__ void async_copy16(const void* g, void* l) {
    __builtin_amdgcn_global_load_lds(
        (const __attribute__((address_space(1))) void*)g,
        (__attribute__((address_space(3))) void*)l, 16, 0, 0);
}

// scale one packed bf16-pair by w (f32 math), repack
__device__ __forceinline__ unsigned int scale_pair(unsigned int u, float w) {
    float lo = __uint_as_float(u << 16) * w;
    float hi = __uint_as_float(u & 0xFFFF0000u) * w;
    return pk2(lo, hi);
}

// ------- Kernel 1 (fused): gating -> wbuf[T,8] + x->Xbf  |  build Bt -------
// blocks 0..511: gating+cvt (64 tokens each). blocks 512..1023: Bt transpose.
__global__ __launch_bounds__(256) void gating_cvt_bt(
    const float* __restrict__ x, const float* __restrict__ Wg,
    const float* __restrict__ bg, const float* __restrict__ Wt,
    const float* __restrict__ bt, float* __restrict__ wbuf,
    unsigned short* __restrict__ Xbf,
    const float* __restrict__ Wexp, unsigned short* __restrict__ Bt)
{
    __shared__ float sW[512 * 12];
    const int tid = threadIdx.x;

    if (blockIdx.x >= 512) {
        // ---------------- build_bt part ----------------
        float(*tile)[65] = (float(*)[65])sW;  // 64x65 floats < 6144
        const int bb = blockIdx.x - 512;
        const int k0 = (bb & 63) * 64;
        const int n0 = (bb >> 6) * 64;
        const int r = tid >> 4, cq = tid & 15;
#pragma unroll
        for (int p = 0; p < 4; ++p) {
            const int rr = p * 16 + r;
            const float4 v = *(const float4*)(Wexp + (size_t)(k0 + rr) * 512 + n0 + cq * 4);
            tile[rr][cq * 4 + 0] = v.x;
            tile[rr][cq * 4 + 1] = v.y;
            tile[rr][cq * 4 + 2] = v.z;
            tile[rr][cq * 4 + 3] = v.w;
        }
        __syncthreads();
        const int rn = tid >> 2;
        const int kq = tid & 3;
        alignas(16) unsigned short buf[16];
#pragma unroll
        for (int j = 0; j < 16; ++j) buf[j] = f2bf(tile[kq * 16 + j][rn]);
        unsigned short* dst = Bt + (size_t)(n0 + rn) * KDIM + k0 + kq * 16;
        *(uint4*)(dst) = *(const uint4*)(buf);
        *(uint4*)(dst + 8) = *(const uint4*)(buf + 8);
        return;
    }

    // ---------------- gating + cvt part ----------------
    for (int i = tid; i < 512 * 9; i += 256) {
        int d = i / 9, e = i - d * 9;
        sW[d * 12 + e] = (e < 8) ? Wg[d * 8 + e] : Wt[d];
    }
    __syncthreads();

    const int t = blockIdx.x * 64 + (tid >> 2);
    const int q = tid & 3;
    float g[9];
#pragma unroll
    for (int e = 0; e < 9; ++e) g[e] = 0.f;

    const float4* xr = (const float4*)(x + (size_t)t * 512 + q * 128);
    for (int i = 0; i < 32; ++i) {
        float4 v = xr[i];
        float xv[4] = {v.x, v.y, v.z, v.w};
        const float* wp = &sW[(q * 128 + i * 4) * 12];
#pragma unroll
        for (int c = 0; c < 4; ++c) {
            const float* w = wp + c * 12;
#pragma unroll
            for (int e = 0; e < 9; ++e) g[e] = fmaf(xv[c], w[e], g[e]);
        }
    }
#pragma unroll
    for (int e = 0; e < 9; ++e) {
        g[e] += __shfl_xor(g[e], 1);
        g[e] += __shfl_xor(g[e], 2);
    }
    if (q == 0) {
#pragma unroll
        for (int e = 0; e < 8; ++e) g[e] += bg[e];
        g[8] += bt[0];
        float m = g[0];
#pragma unroll
        for (int e = 1; e < 8; ++e) m = fmaxf(m, g[e]);
        float s = 0.f;
        float p[8];
#pragma unroll
        for (int e = 0; e < 8; ++e) { p[e] = __expf(g[e] - m); s += p[e]; }
        const float inv = 1.f / s;
        const float thr = 0.25f / (1.f + __expf(-g[8]));
        float w8[8];
        float ws = 0.f;
#pragma unroll
        for (int e = 0; e < 8; ++e) {
            float a = p[e] * inv - thr;
            w8[e] = a > 0.f ? a : 0.f;
            ws += w8[e];
        }
        if (ws == 0.f) ws = 1.f;
        const float invw = 1.f / ws;
        float4 o0, o1;
        o0.x = w8[0] * invw; o0.y = w8[1] * invw; o0.z = w8[2] * invw; o0.w = w8[3] * invw;
        o1.x = w8[4] * invw; o1.y = w8[5] * invw; o1.z = w8[6] * invw; o1.w = w8[7] * invw;
        float4* op = (float4*)(wbuf + (size_t)t * 8);
        op[0] = o0;
        op[1] = o1;
    }

    const size_t base = (size_t)blockIdx.x * 64 * 512;
    const float4* xs = (const float4*)(x + base);
    uint2* xd = (uint2*)(Xbf + base);
#pragma unroll 4
    for (int it = 0; it < 32; ++it) {
        float4 v = xs[it * 256 + tid];
        uint2 pk;
        pk.x = pk2(v.x, v.y);
        pk.y = pk2(v.z, v.w);
        xd[it * 256 + tid] = pk;
    }
}

// ------------- Kernel 2: single-GEMM 256x256, 4-phase pipeline -------------
// LDS element (row,k) at row*64 + ((k/8 ^ (row&7))*8)+k%8 (ushort index).
__global__ __launch_bounds__(512, 2) void moe_gemm(
    const unsigned short* __restrict__ Xbf, const float* __restrict__ wbuf,
    const float* __restrict__ bexp, const unsigned short* __restrict__ Bt,
    float* __restrict__ out)
{
    __shared__ alignas(16) unsigned short Bs[3 * SLOTB];  // 96 KB
    __shared__ alignas(16) unsigned short As[SLOTA];      // 32 KB
    __shared__ float sWbT[8 * 256];                       // 8 KB [e][row]

    const int tid = threadIdx.x;
    const int wave = tid >> 6;      // 0..7
    const int lane = tid & 63;
    const int wm = wave >> 2;       // 0..1: 128-row half
    const int wn = wave & 3;        // 0..3: 64-col quarter
    const int lm = lane & 15;
    const int lq = lane >> 4;
    const int brow = lane >> 3;
    const int cg = (lane & 7) ^ brow;  // lane->global chunk perm (B staging)
    // A-stage thread map: chunk c8, base row r0 (+64*m, m=0..3)
    const int c8 = tid & 7;
    const int r0 = tid >> 3;        // 0..63
    const int swzA = ((c8 ^ (r0 & 7)) << 3);  // r&7 invariant under +64

    // grid 256 = 128 t-tiles x 2 n-halves; XCD-paired (lin%8 = XCD)
    const int lin = blockIdx.x;
    const int g = lin & 7;
    const int j_ = lin >> 3;                  // 0..31
    const int t0 = (g * 16 + (j_ >> 1)) * 256;
    const int n0 = (j_ & 1) * 256;

    // sWbT[e][row] = wbuf[t0+row][e]
    {
        const int row = tid & 255, pr = tid >> 8;  // pr=0/1
        const float4 w4 = *(const float4*)(wbuf + (size_t)(t0 + row) * 8 + pr * 4);
        sWbT[(pr * 4 + 0) * 256 + row] = w4.x;
        sWbT[(pr * 4 + 1) * 256 + row] = w4.y;
        sWbT[(pr * 4 + 2) * 256 + row] = w4.z;
        sWbT[(pr * 4 + 3) * 256 + row] = w4.w;
    }

#define STAGE_B(s_, slot_, i0, i1)                                              \
    {                                                                           \
        const int k0_ = (s_) << 6;                                              \
        _Pragma("unroll")                                                       \
        for (int i = (i0); i < (i1); ++i)                                       \
            async_copy16(Bt + (size_t)(n0 + wave * 32 + i * 8 + brow) * KDIM + k0_ + cg * 8, \
                         Bs + (slot_) * SLOTB + (wave * 32 + i * 8) * 64);      \
    }
#define LOADA_ISSUE(s_)                                                         \
    {                                                                           \
        const int d0_ = ((s_) & 7) << 6;                                        \
        _Pragma("unroll")                                                       \
        for (int m = 0; m < 4; ++m)                                             \
            ar[m] = *(const uint4*)(Xbf + (size_t)(t0 + r0 + m * 64) * 512 + d0_ + c8 * 8); \
    }
#define ASCALE_WRITE(s_)                                                        \
    {                                                                           \
        const int e1 = (s_) >> 3;                                               \
        _Pragma("unroll")                                                       \
        for (int m = 0; m < 4; ++m) {                                           \
            const float w = sWbT[e1 * 256 + r0 + m * 64];                       \
            uint4 o;                                                            \
            o.x = scale_pair(ar[m].x, w);                                       \
            o.y = scale_pair(ar[m].y, w);                                       \
            o.z = scale_pair(ar[m].z, w);                                       \
            o.w = scale_pair(ar[m].w, w);                                       \
            *(uint4*)(As + (r0 + m * 64) * 64 + swzA) = o;                      \
        }                                                                       \
    }
#define READ_A(ih)                                                              \
    {                                                                           \
        _Pragma("unroll")                                                       \
        for (int ii = 0; ii < 4; ++ii)                                          \
            _Pragma("unroll")                                                   \
            for (int kk = 0; kk < 2; ++kk) {                                    \
                const int row = wm * 128 + ((ih) * 4 + ii) * 16 + lm;           \
                const int ch = kk * 4 + lq;                                     \
                af[ii][kk] = *(const short8*)(As + row * 64 + ((ch ^ (row & 7)) << 3)); \
            }                                                                   \
    }
#define READ_B(q_, dst)                                                         \
    {                                                                           \
        _Pragma("unroll")                                                       \
        for (int jj = 0; jj < 2; ++jj)                                          \
            _Pragma("unroll")                                                   \
            for (int kk = 0; kk < 2; ++kk) {                                    \
                const int row = wn * 64 + ((q_) * 2 + jj) * 16 + lm;            \
                const int ch = kk * 4 + lq;                                     \
                dst[jj][kk] = *(const short8*)(Bb + row * 64 + ((ch ^ (row & 7)) << 3)); \
            }                                                                   \
    }
#define MFMA_Q(ih, q_, bq)                                                      \
    {                                                                           \
        __builtin_amdgcn_s_setprio(1);                                          \
        _Pragma("unroll")                                                       \
        for (int ii = 0; ii < 4; ++ii)                                          \
            _Pragma("unroll")                                                   \
            for (int jj = 0; jj < 2; ++jj)                                      \
                _Pragma("unroll")                                               \
                for (int kk = 0; kk < 2; ++kk)                                  \
                    acc[(ih) * 4 + ii][(q_) * 2 + jj] =                         \
                        __builtin_amdgcn_mfma_f32_16x16x32_bf16(                \
                            af[ii][kk], bq[jj][kk], acc[(ih) * 4 + ii][(q_) * 2 + jj], 0, 0, 0); \
        __builtin_amdgcn_s_setprio(0);                                          \
    }

    floatx4 acc[8][4];
#pragma unroll
    for (int i = 0; i < 8; ++i)
#pragma unroll
        for (int j = 0; j < 4; ++j) acc[i][j] = (floatx4){0.f, 0.f, 0.f, 0.f};

    uint4 ar[4];

    // ---- prologue: A(0) regs first (oldest), then B(0), B(1) ----
    LOADA_ISSUE(0);
    STAGE_B(0, 0, 0, 4);
    STAGE_B(1, 1, 0, 4);
    asm volatile("s_waitcnt vmcnt(8)" ::: "memory");   // A(0) landed
    ASCALE_WRITE(0);
    asm volatile("s_waitcnt vmcnt(4) lgkmcnt(0)" ::: "memory");  // B(0)+LDS writes done
    __builtin_amdgcn_s_barrier();

    int sB = 0;
    for (int s = 0; s < 64; ++s) {
        const int sB1 = (sB == 2) ? 0 : sB + 1;
        const int sB2 = (sB == 0) ? 2 : sB - 1;
        const unsigned short* Bb = Bs + sB * SLOTB;
        short8 af[4][2], b0[2][2], b1[2][2];

        // ---- P0: read a-half0 + b-quad0 ; issue A(s+1) regs ----
        READ_A(0);
        READ_B(0, b0);
        if (s < 63) LOADA_ISSUE(s + 1);
        __builtin_amdgcn_s_barrier();
        MFMA_Q(0, 0, b0);
        __builtin_amdgcn_s_barrier();

        // ---- P1: read b-quad1 ; issue B(s+2) half ----
        READ_B(1, b1);
        if (s < 62) STAGE_B(s + 2, sB2, 0, 2);
        __builtin_amdgcn_s_barrier();
        MFMA_Q(0, 1, b1);
        __builtin_amdgcn_s_barrier();

        // ---- P2: read a-half1 ; issue B(s+2) half ----
        READ_A(1);
        if (s < 62) STAGE_B(s + 2, sB2, 2, 4);
        __builtin_amdgcn_s_barrier();
        MFMA_Q(1, 1, b1);
        __builtin_amdgcn_s_barrier();

        // ---- P3: drain older loads; scale+write A(s+1); reload b-quad0 ----
        if (s < 62) {
            asm volatile("s_waitcnt vmcnt(4)" ::: "memory");  // drains B(s+1)+A regs
        } else if (s == 62) {
            asm volatile("s_waitcnt vmcnt(0)" ::: "memory");
        }
        if (s < 63) ASCALE_WRITE(s + 1);
        READ_B(0, b0);
        __builtin_amdgcn_s_barrier();
        MFMA_Q(1, 0, b0);
        asm volatile("s_waitcnt lgkmcnt(0)" ::: "memory");  // A ds_writes visible
        __builtin_amdgcn_s_barrier();

        sB = sB1;
    }

    // ---- epilogue: out = acc + sum_e w[t,e]*b_exp[e,col] ----
    float bc[4][8];
#pragma unroll
    for (int j = 0; j < 4; ++j) {
        const int col = n0 + wn * 64 + j * 16 + lm;
#pragma unroll
        for (int e = 0; e < 8; ++e) bc[j][e] = bexp[e * 512 + col];
    }
#pragma unroll
    for (int i = 0; i < 8; ++i)
#pragma unroll
        for (int r = 0; r < 4; ++r) {
            const int rowl = wm * 128 + i * 16 + lq * 4 + r;
            const float4 w0 = *(const float4*)(wbuf + (size_t)(t0 + rowl) * 8);
            const float4 w1 = *(const float4*)(wbuf + (size_t)(t0 + rowl) * 8 + 4);
            float* op = out + (size_t)(t0 + rowl) * 512 + n0 + wn * 64 + lm;
#pragma unroll
            for (int j = 0; j < 4; ++j) {
                float bias = w0.x * bc[j][0];
                bias = fmaf(w0.y, bc[j][1], bias);
                bias = fmaf(w0.z, bc[j][2], bias);
                bias = fmaf(w0.w, bc[j][3], bias);
                bias = fmaf(w1.x, bc[j][4], bias);
                bias = fmaf(w1.y, bc[j][5], bias);
                bias = fmaf(w1.z, bc[j][6], bias);
                bias = fmaf(w1.w, bc[j][7], bias);
                op[j * 16] = acc[i][j][r] + bias;
            }
        }
#undef STAGE_B
#undef LOADA_ISSUE
#undef ASCALE_WRITE
#undef READ_A
#undef READ_B
#undef MFMA_Q
}

extern "C" void kernel_launch(void* const* d_in, const int* in_sizes, int n_in,
                              void* d_out, int out_size, void* d_ws, size_t ws_size,
                              hipStream_t stream) {
    const float* x   = (const float*)d_in[0];
    const float* Wg  = (const float*)d_in[1];
    const float* bg  = (const float*)d_in[2];
    const float* Wt  = (const float*)d_in[3];
    const float* bt  = (const float*)d_in[4];
    const float* Wex = (const float*)d_in[5];
    const float* bex = (const float*)d_in[6];
    float* out = (float*)d_out;

    // ws layout: Xbf bf16 [32768][512] = 32 MB; Bt bf16 [512][4096] = 4 MB;
    //            wbuf fp32 [32768][8] = 1 MB.  Total 37 MB.
    unsigned short* Xbf = (unsigned short*)d_ws;
    unsigned short* Bt  = (unsigned short*)((char*)d_ws + (size_t)T_TOKENS * DDIM * 2);
    float* wbuf = (float*)((char*)d_ws + (size_t)T_TOKENS * DDIM * 2
                                       + (size_t)DDIM * KDIM * 2);

    gating_cvt_bt<<<1024, 256, 0, stream>>>(x, Wg, bg, Wt, bt, wbuf, Xbf, Wex, Bt);
    moe_gemm<<<256, 512, 0, stream>>>(Xbf, wbuf, bex, Bt, out);
}

// Round 9
// 282.694 us; speedup vs baseline: 1.5627x; 1.0142x over previous
//
#include <hip/hip_runtime.h>

// AdaMoeLayer: B=8,S=4096,D=512,E=8 -> T=32768 tokens
// Round 11: kernel-1 rewrite (was ~125us, roofline ~16us); moe_gemm UNCHANGED
// from R10 (162us, verified).
//  Kernel 1 (gating): one WAVE per token. Lane l owns x[t, 8l..8l+8]:
//   - x read once, wave-contiguous (2KB/wave-load, fully coalesced)
//   - gate weights in VGPRs (lane l needs Wg rows 8l..8l+8 = Wg[64l..64l+64),
//     lane-contiguous float4s; no LDS in the inner loop)
//   - 72 fma + 9x6 shfl_xor reduce per token; lane-0 softmax/threshold
//   - bf16 cvt+Xbf store fused on the same registers (no second x pass)
//  Kernel 1 (blocks >=512): Bt transpose, unchanged from R10.
//  Kernel 2: R10 single-GEMM 256x256 4-phase pipeline, byte-identical.

#define T_TOKENS 32768
#define DDIM 512
#define KDIM 4096
#define SLOTB 16384  // ushorts per B slot (256 rows x 64 k)
#define SLOTA 16384  // ushorts A slot (256 rows x 64 k)

typedef __attribute__((ext_vector_type(8))) short short8;
typedef __attribute__((ext_vector_type(4))) float floatx4;
typedef __bf16 bf16x2 __attribute__((ext_vector_type(2)));

__device__ __forceinline__ unsigned short f2bf(float f) {
    unsigned int u = __float_as_uint(f);
    u += 0x7FFFu + ((u >> 16) & 1u);   // RNE
    return (unsigned short)(u >> 16);
}

__device__ __forceinline__ unsigned int pk2(float a, float b) {
#if __has_builtin(__builtin_amdgcn_cvt_pk_bf16_f32)
    bf16x2 v = __builtin_amdgcn_cvt_pk_bf16_f32(a, b);
    return __builtin_bit_cast(unsigned int, v);
#else
    return (unsigned int)f2bf(a) | ((unsigned int)f2bf(b) << 16);
#endif
}

__device__ __forceinline__ void async_copy16(const void* g, void* l) {
    __builtin_amdgcn_global_load_lds(
        (const __attribute__((address_space(1))) void*)g,
        (__attribute__((address_space(3))) void*)l, 16, 0, 0);
}

// scale one packed bf16-pair by w (f32 math), repack
__device__ __forceinline__ unsigned int scale_pair(unsigned int u, float w) {
    float lo = __uint_as_float(u << 16) * w;
    float hi = __uint_as_float(u & 0xFFFF0000u) * w;
    return pk2(lo, hi);
}

// ------- Kernel 1 (fused): gating -> wbuf[T,8] + x->Xbf  |  build Bt -------
// blocks 0..511: gating+cvt (64 tokens each, wave-per-token). 512..1023: Bt.
__global__ __launch_bounds__(256) void gating_cvt_bt(
    const float* __restrict__ x, const float* __restrict__ Wg,
    const float* __restrict__ bg, const float* __restrict__ Wt,
    const float* __restrict__ bt, float* __restrict__ wbuf,
    unsigned short* __restrict__ Xbf,
    const float* __restrict__ Wexp, unsigned short* __restrict__ Bt)
{
    const int tid = threadIdx.x;

    if (blockIdx.x >= 512) {
        // ---------------- build_bt part (unchanged, R10-verified) ----------
        __shared__ float tile[64][65];
        const int bb = blockIdx.x - 512;
        const int k0 = (bb & 63) * 64;
        const int n0 = (bb >> 6) * 64;
        const int r = tid >> 4, cq = tid & 15;
#pragma unroll
        for (int p = 0; p < 4; ++p) {
            const int rr = p * 16 + r;
            const float4 v = *(const float4*)(Wexp + (size_t)(k0 + rr) * 512 + n0 + cq * 4);
            tile[rr][cq * 4 + 0] = v.x;
            tile[rr][cq * 4 + 1] = v.y;
            tile[rr][cq * 4 + 2] = v.z;
            tile[rr][cq * 4 + 3] = v.w;
        }
        __syncthreads();
        const int rn = tid >> 2;
        const int kq = tid & 3;
        alignas(16) unsigned short buf[16];
#pragma unroll
        for (int j = 0; j < 16; ++j) buf[j] = f2bf(tile[kq * 16 + j][rn]);
        unsigned short* dst = Bt + (size_t)(n0 + rn) * KDIM + k0 + kq * 16;
        *(uint4*)(dst) = *(const uint4*)(buf);
        *(uint4*)(dst + 8) = *(const uint4*)(buf + 8);
        return;
    }

    // ---------------- gating + cvt: wave-per-token -----------------------
    const int wv = tid >> 6;      // wave 0..3
    const int lane = tid & 63;

    // Weights to VGPRs: lane l covers d = 8l..8l+7.
    // Wg[d][e] row-major: rows 8l.. -> Wg[64l .. 64l+64), lane-contiguous.
    float4 wg[16];
    {
        const float4* wgp = (const float4*)(Wg + lane * 64);
#pragma unroll
        for (int c = 0; c < 16; ++c) wg[c] = wgp[c];
    }
    const float4 wt0 = *(const float4*)(Wt + lane * 8);
    const float4 wt1 = *(const float4*)(Wt + lane * 8 + 4);
    const float bgv[8] = {bg[0], bg[1], bg[2], bg[3], bg[4], bg[5], bg[6], bg[7]};
    const float btv = bt[0];

    for (int it = 0; it < 16; ++it) {
        const int t = blockIdx.x * 64 + wv * 16 + it;
        const float* xp = x + (size_t)t * 512 + lane * 8;
        const float4 a0 = *(const float4*)(xp);
        const float4 a1 = *(const float4*)(xp + 4);

        // fused cvt: single x read feeds both Xbf and gating
        uint2 pk0, pk1;
        pk0.x = pk2(a0.x, a0.y);
        pk0.y = pk2(a0.z, a0.w);
        pk1.x = pk2(a1.x, a1.y);
        pk1.y = pk2(a1.z, a1.w);
        uint2* xd = (uint2*)(Xbf + (size_t)t * 512 + lane * 8);
        xd[0] = pk0;
        xd[1] = pk1;

        // 9 partial dots over this lane's 8 elements
        const float xv[8] = {a0.x, a0.y, a0.z, a0.w, a1.x, a1.y, a1.z, a1.w};
        const float wtv[8] = {wt0.x, wt0.y, wt0.z, wt0.w, wt1.x, wt1.y, wt1.z, wt1.w};
        float g[9];
#pragma unroll
        for (int e = 0; e < 9; ++e) g[e] = 0.f;
#pragma unroll
        for (int j = 0; j < 8; ++j) {
            const float4 wlo = wg[j * 2];
            const float4 whi = wg[j * 2 + 1];
            g[0] = fmaf(xv[j], wlo.x, g[0]);
            g[1] = fmaf(xv[j], wlo.y, g[1]);
            g[2] = fmaf(xv[j], wlo.z, g[2]);
            g[3] = fmaf(xv[j], wlo.w, g[3]);
            g[4] = fmaf(xv[j], whi.x, g[4]);
            g[5] = fmaf(xv[j], whi.y, g[5]);
            g[6] = fmaf(xv[j], whi.z, g[6]);
            g[7] = fmaf(xv[j], whi.w, g[7]);
            g[8] = fmaf(xv[j], wtv[j], g[8]);
        }
        // full-wave tree reduce (all lanes end with the total)
#pragma unroll
        for (int e = 0; e < 9; ++e) {
            g[e] += __shfl_xor(g[e], 1);
            g[e] += __shfl_xor(g[e], 2);
            g[e] += __shfl_xor(g[e], 4);
            g[e] += __shfl_xor(g[e], 8);
            g[e] += __shfl_xor(g[e], 16);
            g[e] += __shfl_xor(g[e], 32);
        }
        if (lane == 0) {
#pragma unroll
            for (int e = 0; e < 8; ++e) g[e] += bgv[e];
            g[8] += btv;
            float m = g[0];
#pragma unroll
            for (int e = 1; e < 8; ++e) m = fmaxf(m, g[e]);
            float s = 0.f;
            float p[8];
#pragma unroll
            for (int e = 0; e < 8; ++e) { p[e] = __expf(g[e] - m); s += p[e]; }
            const float inv = 1.f / s;
            const float thr = 0.25f / (1.f + __expf(-g[8]));
            float w8[8];
            float ws = 0.f;
#pragma unroll
            for (int e = 0; e < 8; ++e) {
                float a = p[e] * inv - thr;
                w8[e] = a > 0.f ? a : 0.f;
                ws += w8[e];
            }
            if (ws == 0.f) ws = 1.f;
            const float invw = 1.f / ws;
            float4 o0, o1;
            o0.x = w8[0] * invw; o0.y = w8[1] * invw; o0.z = w8[2] * invw; o0.w = w8[3] * invw;
            o1.x = w8[4] * invw; o1.y = w8[5] * invw; o1.z = w8[6] * invw; o1.w = w8[7] * invw;
            float4* op = (float4*)(wbuf + (size_t)t * 8);
            op[0] = o0;
            op[1] = o1;
        }
    }
}

// ------------- Kernel 2: single-GEMM 256x256, 4-phase pipeline -------------
// (byte-identical to R10 — 162us verified)
// LDS element (row,k) at row*64 + ((k/8 ^ (row&7))*8)+k%8 (ushort index).
__global__ __launch_bounds__(512, 2) void moe_gemm(
    const unsigned short* __restrict__ Xbf, const float* __restrict__ wbuf,
    const float* __restrict__ bexp, const unsigned short* __restrict__ Bt,
    float* __restrict__ out)
{
    __shared__ alignas(16) unsigned short Bs[3 * SLOTB];  // 96 KB
    __shared__ alignas(16) unsigned short As[SLOTA];      // 32 KB
    __shared__ float sWbT[8 * 256];                       // 8 KB [e][row]

    const int tid = threadIdx.x;
    const int wave = tid >> 6;      // 0..7
    const int lane = tid & 63;
    const int wm = wave >> 2;       // 0..1: 128-row half
    const int wn = wave & 3;        // 0..3: 64-col quarter
    const int lm = lane & 15;
    const int lq = lane >> 4;
    const int brow = lane >> 3;
    const int cg = (lane & 7) ^ brow;  // lane->global chunk perm (B staging)
    const int c8 = tid & 7;
    const int r0 = tid >> 3;        // 0..63
    const int swzA = ((c8 ^ (r0 & 7)) << 3);  // r&7 invariant under +64

    const int lin = blockIdx.x;
    const int g = lin & 7;
    const int j_ = lin >> 3;                  // 0..31
    const int t0 = (g * 16 + (j_ >> 1)) * 256;
    const int n0 = (j_ & 1) * 256;

    {
        const int row = tid & 255, pr = tid >> 8;  // pr=0/1
        const float4 w4 = *(const float4*)(wbuf + (size_t)(t0 + row) * 8 + pr * 4);
        sWbT[(pr * 4 + 0) * 256 + row] = w4.x;
        sWbT[(pr * 4 + 1) * 256 + row] = w4.y;
        sWbT[(pr * 4 + 2) * 256 + row] = w4.z;
        sWbT[(pr * 4 + 3) * 256 + row] = w4.w;
    }

#define STAGE_B(s_, slot_, i0, i1)                                              \
    {                                                                           \
        const int k0_ = (s_) << 6;                                              \
        _Pragma("unroll")                                                       \
        for (int i = (i0); i < (i1); ++i)                                       \
            async_copy16(Bt + (size_t)(n0 + wave * 32 + i * 8 + brow) * KDIM + k0_ + cg * 8, \
                         Bs + (slot_) * SLOTB + (wave * 32 + i * 8) * 64);      \
    }
#define LOADA_ISSUE(s_)                                                         \
    {                                                                           \
        const int d0_ = ((s_) & 7) << 6;                                        \
        _Pragma("unroll")                                                       \
        for (int m = 0; m < 4; ++m)                                             \
            ar[m] = *(const uint4*)(Xbf + (size_t)(t0 + r0 + m * 64) * 512 + d0_ + c8 * 8); \
    }
#define ASCALE_WRITE(s_)                                                        \
    {                                                                           \
        const int e1 = (s_) >> 3;                                               \
        _Pragma("unroll")                                                       \
        for (int m = 0; m < 4; ++m) {                                           \
            const float w = sWbT[e1 * 256 + r0 + m * 64];                       \
            uint4 o;                                                            \
            o.x = scale_pair(ar[m].x, w);                                       \
            o.y = scale_pair(ar[m].y, w);                                       \
            o.z = scale_pair(ar[m].z, w);                                       \
            o.w = scale_pair(ar[m].w, w);                                       \
            *(uint4*)(As + (r0 + m * 64) * 64 + swzA) = o;                      \
        }                                                                       \
    }
#define READ_A(ih)                                                              \
    {                                                                           \
        _Pragma("unroll")                                                       \
        for (int ii = 0; ii < 4; ++ii)                                          \
            _Pragma("unroll")                                                   \
            for (int kk = 0; kk < 2; ++kk) {                                    \
                const int row = wm * 128 + ((ih) * 4 + ii) * 16 + lm;           \
                const int ch = kk * 4 + lq;                                     \
                af[ii][kk] = *(const short8*)(As + row * 64 + ((ch ^ (row & 7)) << 3)); \
            }                                                                   \
    }
#define READ_B(q_, dst)                                                         \
    {                                                                           \
        _Pragma("unroll")                                                       \
        for (int jj = 0; jj < 2; ++jj)                                          \
            _Pragma("unroll")                                                   \
            for (int kk = 0; kk < 2; ++kk) {                                    \
                const int row = wn * 64 + ((q_) * 2 + jj) * 16 + lm;            \
                const int ch = kk * 4 + lq;                                     \
                dst[jj][kk] = *(const short8*)(Bb + row * 64 + ((ch ^ (row & 7)) << 3)); \
            }                                                                   \
    }
#define MFMA_Q(ih, q_, bq)                                                      \
    {                                                                           \
        __builtin_amdgcn_s_setprio(1);                                          \
        _Pragma("unroll")                                                       \
        for (int ii = 0; ii < 4; ++ii)                                          \
            _Pragma("unroll")                                                   \
            for (int jj = 0; jj < 2; ++jj)                                      \
                _Pragma("unroll")                                               \
                for (int kk = 0; kk < 2; ++kk)                                  \
                    acc[(ih) * 4 + ii][(q_) * 2 + jj] =                         \
                        __builtin_amdgcn_mfma_f32_16x16x32_bf16(                \
                            af[ii][kk], bq[jj][kk], acc[(ih) * 4 + ii][(q_) * 2 + jj], 0, 0, 0); \
        __builtin_amdgcn_s_setprio(0);                                          \
    }

    floatx4 acc[8][4];
#pragma unroll
    for (int i = 0; i < 8; ++i)
#pragma unroll
        for (int j = 0; j < 4; ++j) acc[i][j] = (floatx4){0.f, 0.f, 0.f, 0.f};

    uint4 ar[4];

    LOADA_ISSUE(0);
    STAGE_B(0, 0, 0, 4);
    STAGE_B(1, 1, 0, 4);
    asm volatile("s_waitcnt vmcnt(8)" ::: "memory");   // A(0) landed
    ASCALE_WRITE(0);
    asm volatile("s_waitcnt vmcnt(4) lgkmcnt(0)" ::: "memory");  // B(0)+LDS writes done
    __builtin_amdgcn_s_barrier();

    int sB = 0;
    for (int s = 0; s < 64; ++s) {
        const int sB1 = (sB == 2) ? 0 : sB + 1;
        const int sB2 = (sB == 0) ? 2 : sB - 1;
        const unsigned short* Bb = Bs + sB * SLOTB;
        short8 af[4][2], b0[2][2], b1[2][2];

        // ---- P0: read a-half0 + b-quad0 ; issue A(s+1) regs ----
        READ_A(0);
        READ_B(0, b0);
        if (s < 63) LOADA_ISSUE(s + 1);
        __builtin_amdgcn_s_barrier();
        MFMA_Q(0, 0, b0);
        __builtin_amdgcn_s_barrier();

        // ---- P1: read b-quad1 ; issue B(s+2) half ----
        READ_B(1, b1);
        if (s < 62) STAGE_B(s + 2, sB2, 0, 2);
        __builtin_amdgcn_s_barrier();
        MFMA_Q(0, 1, b1);
        __builtin_amdgcn_s_barrier();

        // ---- P2: read a-half1 ; issue B(s+2) half ----
        READ_A(1);
        if (s < 62) STAGE_B(s + 2, sB2, 2, 4);
        __builtin_amdgcn_s_barrier();
        MFMA_Q(1, 1, b1);
        __builtin_amdgcn_s_barrier();

        // ---- P3: drain older loads; scale+write A(s+1); reload b-quad0 ----
        if (s < 62) {
            asm volatile("s_waitcnt vmcnt(4)" ::: "memory");  // drains B(s+1)+A regs
        } else if (s == 62) {
            asm volatile("s_waitcnt vmcnt(0)" ::: "memory");
        }
        if (s < 63) ASCALE_WRITE(s + 1);
        READ_B(0, b0);
        __builtin_amdgcn_s_barrier();
        MFMA_Q(1, 0, b0);
        asm volatile("s_waitcnt lgkmcnt(0)" ::: "memory");  // A ds_writes visible
        __builtin_amdgcn_s_barrier();

        sB = sB1;
    }

    // ---- epilogue: out = acc + sum_e w[t,e]*b_exp[e,col] ----
    float bc[4][8];
#pragma unroll
    for (int j = 0; j < 4; ++j) {
        const int col = n0 + wn * 64 + j * 16 + lm;
#pragma unroll
        for (int e = 0; e < 8; ++e) bc[j][e] = bexp[e * 512 + col];
    }
#pragma unroll
    for (int i = 0; i < 8; ++i)
#pragma unroll
        for (int r = 0; r < 4; ++r) {
            const int rowl = wm * 128 + i * 16 + lq * 4 + r;
            const float4 w0 = *(const float4*)(wbuf + (size_t)(t0 + rowl) * 8);
            const float4 w1 = *(const float4*)(wbuf + (size_t)(t0 + rowl) * 8 + 4);
            float* op = out + (size_t)(t0 + rowl) * 512 + n0 + wn * 64 + lm;
#pragma unroll
            for (int j = 0; j < 4; ++j) {
                float bias = w0.x * bc[j][0];
                bias = fmaf(w0.y, bc[j][1], bias);
                bias = fmaf(w0.z, bc[j][2], bias);
                bias = fmaf(w0.w, bc[j][3], bias);
                bias = fmaf(w1.x, bc[j][4], bias);
                bias = fmaf(w1.y, bc[j][5], bias);
                bias = fmaf(w1.z, bc[j][6], bias);
                bias = fmaf(w1.w, bc[j][7], bias);
                op[j * 16] = acc[i][j][r] + bias;
            }
        }
#undef STAGE_B
#undef LOADA_ISSUE
#undef ASCALE_WRITE
#undef READ_A
#undef READ_B
#undef MFMA_Q
}

extern "C" void kernel_launch(void* const* d_in, const int* in_sizes, int n_in,
                              void* d_out, int out_size, void* d_ws, size_t ws_size,
                              hipStream_t stream) {
    const float* x   = (const float*)d_in[0];
    const float* Wg  = (const float*)d_in[1];
    const float* bg  = (const float*)d_in[2];
    const float* Wt  = (const float*)d_in[3];
    const float* bt  = (const float*)d_in[4];
    const float* Wex = (const float*)d_in[5];
    const float* bex = (const float*)d_in[6];
    float* out = (float*)d_out;

    // ws layout: Xbf bf16 [32768][512] = 32 MB; Bt bf16 [512][4096] = 4 MB;
    //            wbuf fp32 [32768][8] = 1 MB.  Total 37 MB.
    unsigned short* Xbf = (unsigned short*)d_ws;
    unsigned short* Bt  = (unsigned short*)((char*)d_ws + (size_t)T_TOKENS * DDIM * 2);
    float* wbuf = (float*)((char*)d_ws + (size_t)T_TOKENS * DDIM * 2
                                       + (size_t)DDIM * KDIM * 2);

    gating_cvt_bt<<<1024, 256, 0, stream>>>(x, Wg, bg, Wt, bt, wbuf, Xbf, Wex, Bt);
    moe_gemm<<<256, 512, 0, stream>>>(Xbf, wbuf, bex, Bt, out);
}